// Round 9
// baseline (220.757 us; speedup 1.0000x reference)
//
#include <hip/hip_runtime.h>
#include <stdint.h>

typedef __bf16 bf16;
typedef __bf16 bf16x4 __attribute__((ext_vector_type(4)));
typedef __bf16 bf16x8 __attribute__((ext_vector_type(8)));
typedef float f32x4 __attribute__((ext_vector_type(4)));
typedef short short4_t __attribute__((ext_vector_type(4)));

#define MFMA16(a, b, c) __builtin_amdgcn_mfma_f32_16x16x32_bf16((a), (b), (c), 0, 0, 0)

__device__ __forceinline__ f32x4 mfma1k(bf16x4 a, bf16x4 b, f32x4 c) {
    return __builtin_amdgcn_mfma_f32_16x16x16bf16_1k(
        __builtin_bit_cast(short4_t, a), __builtin_bit_cast(short4_t, b), c, 0, 0, 0);
}

#define EMBED 1024
#define SEQ   2048
#define MROWS 4096
#define ATTN_SCALE 0.125f

__device__ __forceinline__ void gl2lds16(const bf16* g, bf16* l) {
    __builtin_amdgcn_global_load_lds(
        (const __attribute__((address_space(1))) void*)g,
        (__attribute__((address_space(3))) void*)l,
        16, 0, 0);
}

// ---------------------------------------------------------------------------
// fused fp32 -> bf16 cast of x + 4 weight matrices (contiguous dst region)
// ---------------------------------------------------------------------------
__global__ __launch_bounds__(256) void cast_all_kernel(
    const float* __restrict__ x,  const float* __restrict__ Wq,
    const float* __restrict__ Wk, const float* __restrict__ Wv,
    const float* __restrict__ Wo, bf16* __restrict__ dst) {
    const int blk = blockIdx.x;
    const float* src;
    size_t so, dofs;
    if (blk < 2048) {
        src = x; so = (size_t)blk * 2048; dofs = so;
    } else {
        const int w = (blk - 2048) >> 9;
        so  = (size_t)((blk - 2048) & 511) * 2048;
        src = (w == 0) ? Wq : (w == 1) ? Wk : (w == 2) ? Wv : Wo;
        dofs = (size_t)(4 + w) * 1024 * 1024 + so;
    }
    const size_t i = (size_t)threadIdx.x * 8;
    float4 a = *(const float4*)(src + so + i);
    float4 b = *(const float4*)(src + so + i + 4);
    bf16x8 o;
    o[0] = (bf16)a.x; o[1] = (bf16)a.y; o[2] = (bf16)a.z; o[3] = (bf16)a.w;
    o[4] = (bf16)b.x; o[5] = (bf16)b.y; o[6] = (bf16)b.z; o[7] = (bf16)b.w;
    *(bf16x8*)(dst + dofs + i) = o;
}

// ---------------------------------------------------------------------------
// Q/K GEMM 128x128 tile, BK=64, 4 waves 2x2, XOR-swizzled LDS.
// ---------------------------------------------------------------------------
template <bool SCALE>
__device__ __forceinline__ void gemm_tile(const bf16* __restrict__ A,
                                          const bf16* __restrict__ W,
                                          const float* __restrict__ bias,
                                          bf16* __restrict__ C,
                                          int m0, int n0) {
    __shared__ bf16 As[128 * 64];
    __shared__ bf16 Bs[128 * 64];

    const int lane = threadIdx.x & 63;
    const int wv   = threadIdx.x >> 6;
    const int wm   = (wv >> 1) * 64;
    const int wn   = (wv & 1) * 64;
    const int fr   = lane & 15;
    const int quad = lane >> 4;
    const int srow = wv * 8 + (lane >> 3);
    const int swz  = (((lane & 7) ^ ((lane >> 3) & 7))) * 8;

    f32x4 acc[4][4];
#pragma unroll
    for (int mt = 0; mt < 4; ++mt)
#pragma unroll
        for (int nt = 0; nt < 4; ++nt)
            acc[mt][nt] = (f32x4){0.f, 0.f, 0.f, 0.f};

    for (int k0 = 0; k0 < 1024; k0 += 64) {
#pragma unroll
        for (int i = 0; i < 4; ++i) {
            gl2lds16(A + (size_t)(m0 + i * 32 + srow) * 1024 + k0 + swz,
                     &As[(i * 32 + wv * 8) * 64]);
            gl2lds16(W + (size_t)(n0 + i * 32 + srow) * 1024 + k0 + swz,
                     &Bs[(i * 32 + wv * 8) * 64]);
        }
        __syncthreads();
#pragma unroll
        for (int ks = 0; ks < 2; ++ks) {
            const int fcol = ((ks * 4 + quad) ^ (fr & 7)) * 8;
            bf16x8 af[4], bfr[4];
#pragma unroll
            for (int t = 0; t < 4; ++t) {
                af[t]  = *(const bf16x8*)&As[(wm + t * 16 + fr) * 64 + fcol];
                bfr[t] = *(const bf16x8*)&Bs[(wn + t * 16 + fr) * 64 + fcol];
            }
#pragma unroll
            for (int mt = 0; mt < 4; ++mt)
#pragma unroll
                for (int nt = 0; nt < 4; ++nt)
                    acc[mt][nt] = MFMA16(af[mt], bfr[nt], acc[mt][nt]);
        }
        __syncthreads();
    }

    float bv[4];
#pragma unroll
    for (int nt = 0; nt < 4; ++nt)
        bv[nt] = bias[n0 + wn + nt * 16 + fr];
    const int row4 = quad * 4;
#pragma unroll
    for (int mt = 0; mt < 4; ++mt)
#pragma unroll
        for (int nt = 0; nt < 4; ++nt)
#pragma unroll
            for (int r = 0; r < 4; ++r) {
                int m = m0 + wm + mt * 16 + row4 + r;
                int n = n0 + wn + nt * 16 + fr;
                float v = acc[mt][nt][r] + bv[nt];
                if (SCALE) v *= ATTN_SCALE;
                C[(size_t)m * 1024 + n] = (bf16)v;
            }
}

__global__ __launch_bounds__(256) void qk_kernel(
    const bf16* __restrict__ x,
    const bf16* __restrict__ Wq, const float* __restrict__ bq,
    const bf16* __restrict__ Wk, const float* __restrict__ bk,
    bf16* __restrict__ Q, bf16* __restrict__ K) {
    const int m0 = blockIdx.x * 128;
    const int n0 = (blockIdx.y & 7) * 128;
    if (blockIdx.y < 8) gemm_tile<true>(x, Wq, bq, Q, m0, n0);
    else                gemm_tile<false>(x, Wk, bk, K, m0, n0);
}

// ---------------------------------------------------------------------------
// V^T GEMM: swapped-operand MFMA + LDS round-trip transpose epilogue
// ---------------------------------------------------------------------------
__global__ __launch_bounds__(256) void v_kernel(
    const bf16* __restrict__ x, const bf16* __restrict__ Wv,
    const float* __restrict__ bias, bf16* __restrict__ VT) {
    const int m0 = blockIdx.x * 128;   // token tile
    const int n0 = blockIdx.y * 128;   // d rows

    __shared__ __align__(16) bf16 smem[128 * 136];
    bf16* As = smem;
    bf16* Bs = smem + 128 * 64;

    const int lane = threadIdx.x & 63;
    const int wv   = threadIdx.x >> 6;
    const int wmW  = (wv >> 1) * 64;
    const int wnT  = (wv & 1) * 64;
    const int f    = lane & 15;
    const int quad = lane >> 4;
    const int srow = wv * 8 + (lane >> 3);
    const int swz  = (((lane & 7) ^ ((lane >> 3) & 7))) * 8;

    f32x4 acc[4][4];
#pragma unroll
    for (int mt = 0; mt < 4; ++mt)
#pragma unroll
        for (int nt = 0; nt < 4; ++nt)
            acc[mt][nt] = (f32x4){0.f, 0.f, 0.f, 0.f};

    for (int k0 = 0; k0 < 1024; k0 += 64) {
#pragma unroll
        for (int i = 0; i < 4; ++i) {
            gl2lds16(x  + (size_t)(m0 + i * 32 + srow) * 1024 + k0 + swz,
                     &As[(i * 32 + wv * 8) * 64]);
            gl2lds16(Wv + (size_t)(n0 + i * 32 + srow) * 1024 + k0 + swz,
                     &Bs[(i * 32 + wv * 8) * 64]);
        }
        __syncthreads();
#pragma unroll
        for (int ks = 0; ks < 2; ++ks) {
            const int fcol = ((ks * 4 + quad) ^ (f & 7)) * 8;
            bf16x8 wf[4], xf[4];
#pragma unroll
            for (int t = 0; t < 4; ++t) {
                wf[t] = *(const bf16x8*)&Bs[(wmW + t * 16 + f) * 64 + fcol];
                xf[t] = *(const bf16x8*)&As[(wnT + t * 16 + f) * 64 + fcol];
            }
#pragma unroll
            for (int mt = 0; mt < 4; ++mt)
#pragma unroll
                for (int nt = 0; nt < 4; ++nt)
                    acc[mt][nt] = MFMA16(wf[mt], xf[nt], acc[mt][nt]);
        }
        __syncthreads();
    }

    float4 b4[4];
#pragma unroll
    for (int mt = 0; mt < 4; ++mt)
        b4[mt] = *(const float4*)&bias[n0 + wmW + mt * 16 + quad * 4];

#pragma unroll
    for (int mt = 0; mt < 4; ++mt)
#pragma unroll
        for (int nt = 0; nt < 4; ++nt) {
            const int tok = wnT + nt * 16 + f;
#pragma unroll
            for (int r = 0; r < 4; ++r) {
                const float bvr = (r == 0) ? b4[mt].x : (r == 1) ? b4[mt].y
                                : (r == 2) ? b4[mt].z : b4[mt].w;
                smem[(wmW + mt * 16 + quad * 4 + r) * 136 + tok] =
                    (bf16)(acc[mt][nt][r] + bvr);
            }
        }
    __syncthreads();

    const int n_r  = threadIdx.x >> 4;
    const int t8   = (threadIdx.x & 15) * 8;
    const int bb   = m0 >> 11;
    const int tokg = (m0 & 2047) + t8;
#pragma unroll
    for (int p = 0; p < 8; ++p) {
        const int n_loc = p * 16 + n_r;
        bf16x8 v = *(const bf16x8*)&smem[n_loc * 136 + t8];
        *(bf16x8*)&VT[((size_t)(bb * 1024 + n0 + n_loc)) * 2048 + tokg] = v;
    }
}

// ---------------------------------------------------------------------------
// O-proj GEMM, 128x64 tile, BK=64, 4 waves 2x2, fp32 out.
// ---------------------------------------------------------------------------
__global__ __launch_bounds__(256) void oproj_kernel(
    const bf16* __restrict__ A, const bf16* __restrict__ W,
    const float* __restrict__ bias, float* __restrict__ C) {
    const int m0 = blockIdx.x * 128;
    const int n0 = blockIdx.y * 64;

    __shared__ bf16 As[128 * 64];
    __shared__ bf16 Bs[64 * 64];

    const int lane = threadIdx.x & 63;
    const int wv   = threadIdx.x >> 6;
    const int wm   = (wv >> 1) * 64;
    const int wn   = (wv & 1) * 32;
    const int fr   = lane & 15;
    const int quad = lane >> 4;
    const int srow = wv * 8 + (lane >> 3);
    const int swz  = (((lane & 7) ^ ((lane >> 3) & 7))) * 8;

    f32x4 acc[4][2];
#pragma unroll
    for (int mt = 0; mt < 4; ++mt)
#pragma unroll
        for (int nt = 0; nt < 2; ++nt)
            acc[mt][nt] = (f32x4){0.f, 0.f, 0.f, 0.f};

    for (int k0 = 0; k0 < 1024; k0 += 64) {
#pragma unroll
        for (int i = 0; i < 4; ++i)
            gl2lds16(A + (size_t)(m0 + i * 32 + srow) * 1024 + k0 + swz,
                     &As[(i * 32 + wv * 8) * 64]);
#pragma unroll
        for (int i = 0; i < 2; ++i)
            gl2lds16(W + (size_t)(n0 + i * 32 + srow) * 1024 + k0 + swz,
                     &Bs[(i * 32 + wv * 8) * 64]);
        __syncthreads();
#pragma unroll
        for (int ks = 0; ks < 2; ++ks) {
            const int fcol = ((ks * 4 + quad) ^ (fr & 7)) * 8;
            bf16x8 af[4], bfr[2];
#pragma unroll
            for (int t = 0; t < 4; ++t)
                af[t] = *(const bf16x8*)&As[(wm + t * 16 + fr) * 64 + fcol];
#pragma unroll
            for (int t = 0; t < 2; ++t)
                bfr[t] = *(const bf16x8*)&Bs[(wn + t * 16 + fr) * 64 + fcol];
#pragma unroll
            for (int mt = 0; mt < 4; ++mt)
#pragma unroll
                for (int nt = 0; nt < 2; ++nt)
                    acc[mt][nt] = MFMA16(af[mt], bfr[nt], acc[mt][nt]);
        }
        __syncthreads();
    }

    float bv[2];
#pragma unroll
    for (int nt = 0; nt < 2; ++nt)
        bv[nt] = bias[n0 + wn + nt * 16 + fr];
    const int row4 = quad * 4;
#pragma unroll
    for (int mt = 0; mt < 4; ++mt)
#pragma unroll
        for (int nt = 0; nt < 2; ++nt)
#pragma unroll
            for (int r = 0; r < 4; ++r) {
                int m = m0 + wm + mt * 16 + row4 + r;
                int n = n0 + wn + nt * 16 + fr;
                C[(size_t)m * 1024 + n] = acc[mt][nt][r] + bv[nt];
            }
}

// ---------------------------------------------------------------------------
// Flash attention v7: 512 threads (8 waves), q-tile 128 (16 q/wave),
// KV tile = 128 (16 steps, 1 barrier each), double-buffered 64 KB LDS,
// S^T formulation, Q pre-scaled, denominator via ones-row MFMA.
// ---------------------------------------------------------------------------
__global__ __launch_bounds__(512) void attn_kernel(
    const bf16* __restrict__ Q, const bf16* __restrict__ K,
    const bf16* __restrict__ VT, bf16* __restrict__ O) {
    const int tid  = threadIdx.x;
    const int lane = tid & 63;
    const int wv   = tid >> 6;       // 0..7
    const int quad = lane >> 4;
    const int f    = lane & 15;
    const int q0   = blockIdx.x * 128;
    const int b    = blockIdx.y >> 4;
    const int h    = blockIdx.y & 15;

    const bf16* Qp = Q + ((size_t)b * SEQ) * 1024 + (size_t)h * 64;
    const bf16* Kp = K + ((size_t)b * SEQ) * 1024 + (size_t)h * 64;
    const bf16* Vp = VT + ((size_t)(b * 1024 + h * 64)) * 2048;   // [d][tok]
    bf16*       Op = O + ((size_t)b * SEQ) * 1024 + (size_t)h * 64;

    __shared__ bf16 Ks[2][128 * 64];    // [kv][d], swizzled 16B groups (16 KB)
    __shared__ bf16 VTs[2][64 * 128];   // [d][kv], swizzled 16B groups (16 KB)

    // Q fragments: wave handles q-row q0 + wv*16 + f (pre-scaled in qk_kernel)
    bf16x8 qf[2];
    {
        const bf16* qrow = Qp + (size_t)(q0 + wv * 16 + f) * 1024;
        qf[0] = *(const bf16x8*)(qrow + quad * 8);
        qf[1] = *(const bf16x8*)(qrow + 32 + quad * 8);
    }

    // K staging: 128 rows x 64 d = 16 KB -> 2 calls of 512 lanes x 16 B
    const int srowK = tid >> 3;                               // 0..63
    const int swzK  = (((tid & 7) ^ ((tid >> 3) & 7))) * 8;
    // VT staging: 64 rows x 128 kv = 16 KB -> 2 calls; row d = i*32 + (tid>>4),
    // phys col16 p = tid&15, source col c = (p&8) | ((p&7) ^ (d&7))
    const int srowV = tid >> 4;                               // 0..31
    const int pV    = tid & 15;
    const int cV    = (pV & 8) | ((pV & 7) ^ (srowV & 7));

    auto stageK = [&](int kv0, int buf) {
#pragma unroll
        for (int i = 0; i < 2; ++i)
            gl2lds16(Kp + (size_t)(kv0 + i * 64 + srowK) * 1024 + swzK,
                     &Ks[buf][i * 4096 + wv * 512]);
    };
    auto stageVT = [&](int kv0, int buf) {
#pragma unroll
        for (int i = 0; i < 2; ++i)
            gl2lds16(Vp + (size_t)(i * 32 + srowV) * 2048 + kv0 + cV * 8,
                     &VTs[buf][i * 4096 + wv * 512]);
    };

    stageK(0, 0);
    stageVT(0, 0);

    f32x4 oacc[4];
#pragma unroll
    for (int t = 0; t < 4; ++t)
        oacc[t] = (f32x4){0.f, 0.f, 0.f, 0.f};
    f32x4 lacc = (f32x4){0.f, 0.f, 0.f, 0.f};
    const bf16x4 onesb = {(bf16)1.f, (bf16)1.f, (bf16)1.f, (bf16)1.f};
    const f32x4  zero4 = (f32x4){0.f, 0.f, 0.f, 0.f};

    const int fcol0 = (quad ^ (f & 7)) * 8;
    const int fcol1 = ((4 + quad) ^ (f & 7)) * 8;

    __syncthreads();

    auto step = [&](int cur, int nextit) {
        if (nextit < SEQ / 128) {          // async prefetch before compute
            stageK(nextit * 128, cur ^ 1);
            stageVT(nextit * 128, cur ^ 1);
        }

        // ---- S^T = K Q^T: 8 tiles of 16 kv x 16 q ----
        f32x4 s[8];
#pragma unroll
        for (int t = 0; t < 8; ++t) {
            bf16x8 k0 = *(const bf16x8*)&Ks[cur][(t * 16 + f) * 64 + fcol0];
            bf16x8 k1 = *(const bf16x8*)&Ks[cur][(t * 16 + f) * 64 + fcol1];
            s[t] = MFMA16(k0, qf[0], zero4);
            s[t] = MFMA16(k1, qf[1], s[t]);
        }

        // ---- P^T = exp(S^T); denominator via ones-row MFMA ----
        bf16x4 pb[8];
#pragma unroll
        for (int t = 0; t < 8; ++t) {
#pragma unroll
            for (int r = 0; r < 4; ++r)
                pb[t][r] = (bf16)__expf(s[t][r]);
            lacc = mfma1k(onesb, pb[t], lacc);
        }

        // ---- O^T += V^T P^T ----
#pragma unroll
        for (int kt = 0; kt < 8; ++kt) {
            const int c  = kt * 2 + (quad >> 1);
            const int p  = (c & 8) | ((c & 7) ^ (f & 7));
            const int po = p * 8 + (quad & 1) * 4;
#pragma unroll
            for (int dt = 0; dt < 4; ++dt) {
                bf16x4 vf = *(const bf16x4*)&VTs[cur][(dt * 16 + f) * 128 + po];
                oacc[dt] = mfma1k(vf, pb[kt], oacc[dt]);
            }
        }
        __syncthreads();
    };

    for (int it = 0; it < SEQ / 128; it += 2) {
        step(0, it + 1);
        step(1, it + 2);
    }

    // ---- normalize + store (lacc col f = denominator for q-row f) ----
    const float inv = 1.0f / lacc[0];
    bf16* orow = Op + (size_t)(q0 + wv * 16 + f) * 1024;
#pragma unroll
    for (int dt = 0; dt < 4; ++dt) {
        bf16x4 ov;
#pragma unroll
        for (int r = 0; r < 4; ++r)
            ov[r] = (bf16)(oacc[dt][r] * inv);
        *(bf16x4*)(orow + dt * 16 + quad * 4) = ov;
    }
}

extern "C" void kernel_launch(void* const* d_in, const int* in_sizes, int n_in,
                              void* d_out, int out_size, void* d_ws, size_t ws_size,
                              hipStream_t stream) {
    const float* x  = (const float*)d_in[0];
    const float* Wq = (const float*)d_in[1];
    const float* bq = (const float*)d_in[2];
    const float* Wk = (const float*)d_in[3];
    const float* bk = (const float*)d_in[4];
    const float* Wv = (const float*)d_in[5];
    const float* bv = (const float*)d_in[6];
    const float* Wo = (const float*)d_in[7];
    const float* bo = (const float*)d_in[8];
    float* out = (float*)d_out;

    bf16* xb  = (bf16*)d_ws;
    bf16* Wqb = xb  + (size_t)MROWS * 1024;
    bf16* Wkb = Wqb + (size_t)1024 * 1024;
    bf16* Wvb = Wkb + (size_t)1024 * 1024;
    bf16* Wob = Wvb + (size_t)1024 * 1024;
    bf16* Q   = Wob + (size_t)1024 * 1024;
    bf16* K   = Q + (size_t)MROWS * 1024;
    bf16* VT  = K + (size_t)MROWS * 1024;   // [B*1024 rows][2048 tokens]
    bf16* O   = VT + (size_t)MROWS * 1024;

    cast_all_kernel<<<4096, 256, 0, stream>>>(x, Wq, Wk, Wv, Wo, xb);

    qk_kernel<<<dim3(32, 16), 256, 0, stream>>>(xb, Wqb, bq, Wkb, bk, Q, K);
    v_kernel<<<dim3(32, 8), 256, 0, stream>>>(xb, Wvb, bv, VT);
    attn_kernel<<<dim3(16, 32), 512, 0, stream>>>(Q, K, VT, O);
    oproj_kernel<<<dim3(32, 16), 256, 0, stream>>>(O, Wob, bo, out);
}

// Round 10
// 201.456 us; speedup vs baseline: 1.0958x; 1.0958x over previous
//
#include <hip/hip_runtime.h>
#include <stdint.h>

typedef __bf16 bf16;
typedef __bf16 bf16x4 __attribute__((ext_vector_type(4)));
typedef __bf16 bf16x8 __attribute__((ext_vector_type(8)));
typedef float f32x4 __attribute__((ext_vector_type(4)));
typedef short short4_t __attribute__((ext_vector_type(4)));

#define MFMA16(a, b, c) __builtin_amdgcn_mfma_f32_16x16x32_bf16((a), (b), (c), 0, 0, 0)

__device__ __forceinline__ f32x4 mfma1k(bf16x4 a, bf16x4 b, f32x4 c) {
    return __builtin_amdgcn_mfma_f32_16x16x16bf16_1k(
        __builtin_bit_cast(short4_t, a), __builtin_bit_cast(short4_t, b), c, 0, 0, 0);
}

#define EMBED 1024
#define SEQ   2048
#define MROWS 4096
#define ATTN_SCALE 0.125f

__device__ __forceinline__ void gl2lds16(const bf16* g, bf16* l) {
    __builtin_amdgcn_global_load_lds(
        (const __attribute__((address_space(1))) void*)g,
        (__attribute__((address_space(3))) void*)l,
        16, 0, 0);
}

// ---------------------------------------------------------------------------
// fused fp32 -> bf16 cast of x + 4 weight matrices (contiguous dst region)
// ---------------------------------------------------------------------------
__global__ __launch_bounds__(256) void cast_all_kernel(
    const float* __restrict__ x,  const float* __restrict__ Wq,
    const float* __restrict__ Wk, const float* __restrict__ Wv,
    const float* __restrict__ Wo, bf16* __restrict__ dst) {
    const int blk = blockIdx.x;
    const float* src;
    size_t so, dofs;
    if (blk < 2048) {
        src = x; so = (size_t)blk * 2048; dofs = so;
    } else {
        const int w = (blk - 2048) >> 9;
        so  = (size_t)((blk - 2048) & 511) * 2048;
        src = (w == 0) ? Wq : (w == 1) ? Wk : (w == 2) ? Wv : Wo;
        dofs = (size_t)(4 + w) * 1024 * 1024 + so;
    }
    const size_t i = (size_t)threadIdx.x * 8;
    float4 a = *(const float4*)(src + so + i);
    float4 b = *(const float4*)(src + so + i + 4);
    bf16x8 o;
    o[0] = (bf16)a.x; o[1] = (bf16)a.y; o[2] = (bf16)a.z; o[3] = (bf16)a.w;
    o[4] = (bf16)b.x; o[5] = (bf16)b.y; o[6] = (bf16)b.z; o[7] = (bf16)b.w;
    *(bf16x8*)(dst + dofs + i) = o;
}

// ---------------------------------------------------------------------------
// Q/K GEMM path: 128x128 tile, BK=64, 4 waves 2x2, XOR-swizzled LDS.
// ---------------------------------------------------------------------------
template <bool SCALE>
__device__ __forceinline__ void gemm_tile(const bf16* __restrict__ A,
                                          const bf16* __restrict__ W,
                                          const float* __restrict__ bias,
                                          bf16* __restrict__ C,
                                          int m0, int n0, bf16* smem) {
    bf16* As = smem;
    bf16* Bs = smem + 128 * 64;

    const int lane = threadIdx.x & 63;
    const int wv   = threadIdx.x >> 6;
    const int wm   = (wv >> 1) * 64;
    const int wn   = (wv & 1) * 64;
    const int fr   = lane & 15;
    const int quad = lane >> 4;
    const int srow = wv * 8 + (lane >> 3);
    const int swz  = (((lane & 7) ^ ((lane >> 3) & 7))) * 8;

    f32x4 acc[4][4];
#pragma unroll
    for (int mt = 0; mt < 4; ++mt)
#pragma unroll
        for (int nt = 0; nt < 4; ++nt)
            acc[mt][nt] = (f32x4){0.f, 0.f, 0.f, 0.f};

    for (int k0 = 0; k0 < 1024; k0 += 64) {
#pragma unroll
        for (int i = 0; i < 4; ++i) {
            gl2lds16(A + (size_t)(m0 + i * 32 + srow) * 1024 + k0 + swz,
                     &As[(i * 32 + wv * 8) * 64]);
            gl2lds16(W + (size_t)(n0 + i * 32 + srow) * 1024 + k0 + swz,
                     &Bs[(i * 32 + wv * 8) * 64]);
        }
        __syncthreads();
#pragma unroll
        for (int ks = 0; ks < 2; ++ks) {
            const int fcol = ((ks * 4 + quad) ^ (fr & 7)) * 8;
            bf16x8 af[4], bfr[4];
#pragma unroll
            for (int t = 0; t < 4; ++t) {
                af[t]  = *(const bf16x8*)&As[(wm + t * 16 + fr) * 64 + fcol];
                bfr[t] = *(const bf16x8*)&Bs[(wn + t * 16 + fr) * 64 + fcol];
            }
#pragma unroll
            for (int mt = 0; mt < 4; ++mt)
#pragma unroll
                for (int nt = 0; nt < 4; ++nt)
                    acc[mt][nt] = MFMA16(af[mt], bfr[nt], acc[mt][nt]);
        }
        __syncthreads();
    }

    float bv[4];
#pragma unroll
    for (int nt = 0; nt < 4; ++nt)
        bv[nt] = bias[n0 + wn + nt * 16 + fr];
    const int row4 = quad * 4;
#pragma unroll
    for (int mt = 0; mt < 4; ++mt)
#pragma unroll
        for (int nt = 0; nt < 4; ++nt)
#pragma unroll
            for (int r = 0; r < 4; ++r) {
                int m = m0 + wm + mt * 16 + row4 + r;
                int n = n0 + wn + nt * 16 + fr;
                float v = acc[mt][nt][r] + bv[nt];
                if (SCALE) v *= ATTN_SCALE;
                C[(size_t)m * 1024 + n] = (bf16)v;
            }
}

// ---------------------------------------------------------------------------
// V^T GEMM path: swapped-operand MFMA + LDS round-trip transpose epilogue
// ---------------------------------------------------------------------------
__device__ __forceinline__ void v_tile(const bf16* __restrict__ x,
                                       const bf16* __restrict__ Wv,
                                       const float* __restrict__ bias,
                                       bf16* __restrict__ VT,
                                       int m0, int n0, bf16* smem) {
    bf16* As = smem;
    bf16* Bs = smem + 128 * 64;

    const int lane = threadIdx.x & 63;
    const int wv   = threadIdx.x >> 6;
    const int wmW  = (wv >> 1) * 64;
    const int wnT  = (wv & 1) * 64;
    const int f    = lane & 15;
    const int quad = lane >> 4;
    const int srow = wv * 8 + (lane >> 3);
    const int swz  = (((lane & 7) ^ ((lane >> 3) & 7))) * 8;

    f32x4 acc[4][4];
#pragma unroll
    for (int mt = 0; mt < 4; ++mt)
#pragma unroll
        for (int nt = 0; nt < 4; ++nt)
            acc[mt][nt] = (f32x4){0.f, 0.f, 0.f, 0.f};

    for (int k0 = 0; k0 < 1024; k0 += 64) {
#pragma unroll
        for (int i = 0; i < 4; ++i) {
            gl2lds16(x  + (size_t)(m0 + i * 32 + srow) * 1024 + k0 + swz,
                     &As[(i * 32 + wv * 8) * 64]);
            gl2lds16(Wv + (size_t)(n0 + i * 32 + srow) * 1024 + k0 + swz,
                     &Bs[(i * 32 + wv * 8) * 64]);
        }
        __syncthreads();
#pragma unroll
        for (int ks = 0; ks < 2; ++ks) {
            const int fcol = ((ks * 4 + quad) ^ (f & 7)) * 8;
            bf16x8 wf[4], xf[4];
#pragma unroll
            for (int t = 0; t < 4; ++t) {
                wf[t] = *(const bf16x8*)&Bs[(wmW + t * 16 + f) * 64 + fcol];
                xf[t] = *(const bf16x8*)&As[(wnT + t * 16 + f) * 64 + fcol];
            }
#pragma unroll
            for (int mt = 0; mt < 4; ++mt)
#pragma unroll
                for (int nt = 0; nt < 4; ++nt)
                    acc[mt][nt] = MFMA16(wf[mt], xf[nt], acc[mt][nt]);
        }
        __syncthreads();
    }

    float4 b4[4];
#pragma unroll
    for (int mt = 0; mt < 4; ++mt)
        b4[mt] = *(const float4*)&bias[n0 + wmW + mt * 16 + quad * 4];

#pragma unroll
    for (int mt = 0; mt < 4; ++mt)
#pragma unroll
        for (int nt = 0; nt < 4; ++nt) {
            const int tok = wnT + nt * 16 + f;
#pragma unroll
            for (int r = 0; r < 4; ++r) {
                const float bvr = (r == 0) ? b4[mt].x : (r == 1) ? b4[mt].y
                                : (r == 2) ? b4[mt].z : b4[mt].w;
                smem[(wmW + mt * 16 + quad * 4 + r) * 136 + tok] =
                    (bf16)(acc[mt][nt][r] + bvr);
            }
        }
    __syncthreads();

    const int n_r  = threadIdx.x >> 4;
    const int t8   = (threadIdx.x & 15) * 8;
    const int bb   = m0 >> 11;
    const int tokg = (m0 & 2047) + t8;
#pragma unroll
    for (int p = 0; p < 8; ++p) {
        const int n_loc = p * 16 + n_r;
        bf16x8 v = *(const bf16x8*)&smem[n_loc * 136 + t8];
        *(bf16x8*)&VT[((size_t)(bb * 1024 + n0 + n_loc)) * 2048 + tokg] = v;
    }
}

// merged Q/K/V projection: 768 blocks -> 3 blocks/CU
__global__ __launch_bounds__(256) void qkv_kernel(
    const bf16* __restrict__ x,
    const bf16* __restrict__ Wq, const float* __restrict__ bq,
    const bf16* __restrict__ Wk, const float* __restrict__ bk,
    const bf16* __restrict__ Wv, const float* __restrict__ bv,
    bf16* __restrict__ Q, bf16* __restrict__ K, bf16* __restrict__ VT) {
    __shared__ __align__(16) bf16 smem[128 * 136];
    const int m0    = blockIdx.x * 128;
    const int which = blockIdx.y >> 3;
    const int n0    = (blockIdx.y & 7) * 128;
    if (which == 0)      gemm_tile<true>(x, Wq, bq, Q, m0, n0, smem);
    else if (which == 1) gemm_tile<false>(x, Wk, bk, K, m0, n0, smem);
    else                 v_tile(x, Wv, bv, VT, m0, n0, smem);
}

// ---------------------------------------------------------------------------
// O-proj GEMM, 128x64 tile, BK=64, 4 waves 2x2, fp32 out.
// ---------------------------------------------------------------------------
__global__ __launch_bounds__(256) void oproj_kernel(
    const bf16* __restrict__ A, const bf16* __restrict__ W,
    const float* __restrict__ bias, float* __restrict__ C) {
    const int m0 = blockIdx.x * 128;
    const int n0 = blockIdx.y * 64;

    __shared__ bf16 As[128 * 64];
    __shared__ bf16 Bs[64 * 64];

    const int lane = threadIdx.x & 63;
    const int wv   = threadIdx.x >> 6;
    const int wm   = (wv >> 1) * 64;
    const int wn   = (wv & 1) * 32;
    const int fr   = lane & 15;
    const int quad = lane >> 4;
    const int srow = wv * 8 + (lane >> 3);
    const int swz  = (((lane & 7) ^ ((lane >> 3) & 7))) * 8;

    f32x4 acc[4][2];
#pragma unroll
    for (int mt = 0; mt < 4; ++mt)
#pragma unroll
        for (int nt = 0; nt < 2; ++nt)
            acc[mt][nt] = (f32x4){0.f, 0.f, 0.f, 0.f};

    for (int k0 = 0; k0 < 1024; k0 += 64) {
#pragma unroll
        for (int i = 0; i < 4; ++i)
            gl2lds16(A + (size_t)(m0 + i * 32 + srow) * 1024 + k0 + swz,
                     &As[(i * 32 + wv * 8) * 64]);
#pragma unroll
        for (int i = 0; i < 2; ++i)
            gl2lds16(W + (size_t)(n0 + i * 32 + srow) * 1024 + k0 + swz,
                     &Bs[(i * 32 + wv * 8) * 64]);
        __syncthreads();
#pragma unroll
        for (int ks = 0; ks < 2; ++ks) {
            const int fcol = ((ks * 4 + quad) ^ (fr & 7)) * 8;
            bf16x8 af[4], bfr[2];
#pragma unroll
            for (int t = 0; t < 4; ++t)
                af[t] = *(const bf16x8*)&As[(wm + t * 16 + fr) * 64 + fcol];
#pragma unroll
            for (int t = 0; t < 2; ++t)
                bfr[t] = *(const bf16x8*)&Bs[(wn + t * 16 + fr) * 64 + fcol];
#pragma unroll
            for (int mt = 0; mt < 4; ++mt)
#pragma unroll
                for (int nt = 0; nt < 2; ++nt)
                    acc[mt][nt] = MFMA16(af[mt], bfr[nt], acc[mt][nt]);
        }
        __syncthreads();
    }

    float bv[2];
#pragma unroll
    for (int nt = 0; nt < 2; ++nt)
        bv[nt] = bias[n0 + wn + nt * 16 + fr];
    const int row4 = quad * 4;
#pragma unroll
    for (int mt = 0; mt < 4; ++mt)
#pragma unroll
        for (int nt = 0; nt < 2; ++nt)
#pragma unroll
            for (int r = 0; r < 4; ++r) {
                int m = m0 + wm + mt * 16 + row4 + r;
                int n = n0 + wn + nt * 16 + fr;
                C[(size_t)m * 1024 + n] = acc[mt][nt][r] + bv[nt];
            }
}

// ---------------------------------------------------------------------------
// Flash attention (R8 config): 512 threads (8 waves), q-tile 128 (16 q/wave),
// KV tile 64, double-buffered 32 KB LDS, S^T formulation, Q pre-scaled,
// denominator via ones-row MFMA, 1 barrier/iter, unroll x2.
// ---------------------------------------------------------------------------
__global__ __launch_bounds__(512) void attn_kernel(
    const bf16* __restrict__ Q, const bf16* __restrict__ K,
    const bf16* __restrict__ VT, bf16* __restrict__ O) {
    const int tid  = threadIdx.x;
    const int lane = tid & 63;
    const int wv   = tid >> 6;       // 0..7
    const int quad = lane >> 4;
    const int f    = lane & 15;
    const int q0   = blockIdx.x * 128;
    const int b    = blockIdx.y >> 4;
    const int h    = blockIdx.y & 15;

    const bf16* Qp = Q + ((size_t)b * SEQ) * 1024 + (size_t)h * 64;
    const bf16* Kp = K + ((size_t)b * SEQ) * 1024 + (size_t)h * 64;
    const bf16* Vp = VT + ((size_t)(b * 1024 + h * 64)) * 2048;   // [d][tok]
    bf16*       Op = O + ((size_t)b * SEQ) * 1024 + (size_t)h * 64;

    __shared__ bf16 Ks[2][64 * 64];    // [kv][d], swizzled 16B groups
    __shared__ bf16 VTs[2][64 * 64];   // [d][kv], swizzled 16B groups

    bf16x8 qf[2];
    {
        const bf16* qrow = Qp + (size_t)(q0 + wv * 16 + f) * 1024;
        qf[0] = *(const bf16x8*)(qrow + quad * 8);
        qf[1] = *(const bf16x8*)(qrow + 32 + quad * 8);
    }

    const int srow = tid >> 3;                              // 0..63
    const int swz  = (((tid & 7) ^ ((tid >> 3) & 7))) * 8;
    auto stageK = [&](int kv0, int buf) {
        gl2lds16(Kp + (size_t)(kv0 + srow) * 1024 + swz, &Ks[buf][wv * 512]);
    };
    auto stageVT = [&](int kv0, int buf) {
        gl2lds16(Vp + (size_t)srow * 2048 + kv0 + swz, &VTs[buf][wv * 512]);
    };

    stageK(0, 0);
    stageVT(0, 0);

    f32x4 oacc[4];
#pragma unroll
    for (int t = 0; t < 4; ++t)
        oacc[t] = (f32x4){0.f, 0.f, 0.f, 0.f};
    f32x4 lacc = (f32x4){0.f, 0.f, 0.f, 0.f};
    const bf16x4 onesb = {(bf16)1.f, (bf16)1.f, (bf16)1.f, (bf16)1.f};
    const f32x4  zero4 = (f32x4){0.f, 0.f, 0.f, 0.f};

    const int fcol0 = (quad ^ (f & 7)) * 8;
    const int fcol1 = ((4 + quad) ^ (f & 7)) * 8;

    __syncthreads();

    auto step = [&](int cur, int nextit) {
        if (nextit < SEQ / 64) {          // async prefetch before compute
            stageK(nextit * 64, cur ^ 1);
            stageVT(nextit * 64, cur ^ 1);
        }

        // ---- S^T = K Q^T: 4 tiles of 16 kv x 16 q ----
        f32x4 s[4];
#pragma unroll
        for (int t = 0; t < 4; ++t) {
            bf16x8 k0 = *(const bf16x8*)&Ks[cur][(t * 16 + f) * 64 + fcol0];
            bf16x8 k1 = *(const bf16x8*)&Ks[cur][(t * 16 + f) * 64 + fcol1];
            s[t] = MFMA16(k0, qf[0], zero4);
            s[t] = MFMA16(k1, qf[1], s[t]);
        }

        // ---- P^T = exp(S^T); denominator via ones-row MFMA ----
        bf16x4 pb[4];
#pragma unroll
        for (int t = 0; t < 4; ++t) {
#pragma unroll
            for (int r = 0; r < 4; ++r)
                pb[t][r] = (bf16)__expf(s[t][r]);
            lacc = mfma1k(onesb, pb[t], lacc);
        }

        // ---- O^T += V^T P^T ----
#pragma unroll
        for (int dt = 0; dt < 4; ++dt) {
#pragma unroll
            for (int kt = 0; kt < 4; ++kt) {
                const int pc = ((kt * 2 + (quad >> 1)) ^ (f & 7)) * 8 + (quad & 1) * 4;
                bf16x4 vf = *(const bf16x4*)&VTs[cur][(dt * 16 + f) * 64 + pc];
                oacc[dt] = mfma1k(vf, pb[kt], oacc[dt]);
            }
        }
        __syncthreads();
    };

    for (int it = 0; it < SEQ / 64; it += 2) {
        step(0, it + 1);
        step(1, it + 2);
    }

    const float inv = 1.0f / lacc[0];
    bf16* orow = Op + (size_t)(q0 + wv * 16 + f) * 1024;
#pragma unroll
    for (int dt = 0; dt < 4; ++dt) {
        bf16x4 ov;
#pragma unroll
        for (int r = 0; r < 4; ++r)
            ov[r] = (bf16)(oacc[dt][r] * inv);
        *(bf16x4*)(orow + dt * 16 + quad * 4) = ov;
    }
}

extern "C" void kernel_launch(void* const* d_in, const int* in_sizes, int n_in,
                              void* d_out, int out_size, void* d_ws, size_t ws_size,
                              hipStream_t stream) {
    const float* x  = (const float*)d_in[0];
    const float* Wq = (const float*)d_in[1];
    const float* bq = (const float*)d_in[2];
    const float* Wk = (const float*)d_in[3];
    const float* bk = (const float*)d_in[4];
    const float* Wv = (const float*)d_in[5];
    const float* bv = (const float*)d_in[6];
    const float* Wo = (const float*)d_in[7];
    const float* bo = (const float*)d_in[8];
    float* out = (float*)d_out;

    bf16* xb  = (bf16*)d_ws;
    bf16* Wqb = xb  + (size_t)MROWS * 1024;
    bf16* Wkb = Wqb + (size_t)1024 * 1024;
    bf16* Wvb = Wkb + (size_t)1024 * 1024;
    bf16* Wob = Wvb + (size_t)1024 * 1024;
    bf16* Q   = Wob + (size_t)1024 * 1024;
    bf16* K   = Q + (size_t)MROWS * 1024;
    bf16* VT  = K + (size_t)MROWS * 1024;   // [B*1024 rows][2048 tokens]
    bf16* O   = VT + (size_t)MROWS * 1024;

    cast_all_kernel<<<4096, 256, 0, stream>>>(x, Wq, Wk, Wv, Wo, xb);

    qkv_kernel<<<dim3(32, 24), 256, 0, stream>>>(xb, Wqb, bq, Wkb, bk, Wvb, bv, Q, K, VT);
    attn_kernel<<<dim3(16, 32), 512, 0, stream>>>(Q, K, VT, O);
    oproj_kernel<<<dim3(32, 16), 256, 0, stream>>>(O, Wob, bo, out);
}

// Round 11
// 200.762 us; speedup vs baseline: 1.0996x; 1.0035x over previous
//
#include <hip/hip_runtime.h>
#include <stdint.h>

typedef __bf16 bf16;
typedef __bf16 bf16x4 __attribute__((ext_vector_type(4)));
typedef __bf16 bf16x8 __attribute__((ext_vector_type(8)));
typedef float f32x4 __attribute__((ext_vector_type(4)));
typedef short short4_t __attribute__((ext_vector_type(4)));

#define MFMA16(a, b, c) __builtin_amdgcn_mfma_f32_16x16x32_bf16((a), (b), (c), 0, 0, 0)

__device__ __forceinline__ f32x4 mfma1k(bf16x4 a, bf16x4 b, f32x4 c) {
    return __builtin_amdgcn_mfma_f32_16x16x16bf16_1k(
        __builtin_bit_cast(short4_t, a), __builtin_bit_cast(short4_t, b), c, 0, 0, 0);
}

#define EMBED 1024
#define SEQ   2048
#define MROWS 4096
#define ATTN_SCALE 0.125f

__device__ __forceinline__ void gl2lds16(const bf16* g, bf16* l) {
    __builtin_amdgcn_global_load_lds(
        (const __attribute__((address_space(1))) void*)g,
        (__attribute__((address_space(3))) void*)l,
        16, 0, 0);
}

// ---------------------------------------------------------------------------
// fused fp32 -> bf16 cast of x + 4 weight matrices (contiguous dst region)
// ---------------------------------------------------------------------------
__global__ __launch_bounds__(256) void cast_all_kernel(
    const float* __restrict__ x,  const float* __restrict__ Wq,
    const float* __restrict__ Wk, const float* __restrict__ Wv,
    const float* __restrict__ Wo, bf16* __restrict__ dst) {
    const int blk = blockIdx.x;
    const float* src;
    size_t so, dofs;
    if (blk < 2048) {
        src = x; so = (size_t)blk * 2048; dofs = so;
    } else {
        const int w = (blk - 2048) >> 9;
        so  = (size_t)((blk - 2048) & 511) * 2048;
        src = (w == 0) ? Wq : (w == 1) ? Wk : (w == 2) ? Wv : Wo;
        dofs = (size_t)(4 + w) * 1024 * 1024 + so;
    }
    const size_t i = (size_t)threadIdx.x * 8;
    float4 a = *(const float4*)(src + so + i);
    float4 b = *(const float4*)(src + so + i + 4);
    bf16x8 o;
    o[0] = (bf16)a.x; o[1] = (bf16)a.y; o[2] = (bf16)a.z; o[3] = (bf16)a.w;
    o[4] = (bf16)b.x; o[5] = (bf16)b.y; o[6] = (bf16)b.z; o[7] = (bf16)b.w;
    *(bf16x8*)(dst + dofs + i) = o;
}

// ---------------------------------------------------------------------------
// Q/K GEMM path: 128x128 tile, BK=64, 4 waves 2x2, XOR-swizzled LDS.
// ---------------------------------------------------------------------------
template <bool SCALE>
__device__ __forceinline__ void gemm_tile(const bf16* __restrict__ A,
                                          const bf16* __restrict__ W,
                                          const float* __restrict__ bias,
                                          bf16* __restrict__ C,
                                          int m0, int n0, bf16* smem) {
    bf16* As = smem;
    bf16* Bs = smem + 128 * 64;

    const int lane = threadIdx.x & 63;
    const int wv   = threadIdx.x >> 6;
    const int wm   = (wv >> 1) * 64;
    const int wn   = (wv & 1) * 64;
    const int fr   = lane & 15;
    const int quad = lane >> 4;
    const int srow = wv * 8 + (lane >> 3);
    const int swz  = (((lane & 7) ^ ((lane >> 3) & 7))) * 8;

    f32x4 acc[4][4];
#pragma unroll
    for (int mt = 0; mt < 4; ++mt)
#pragma unroll
        for (int nt = 0; nt < 4; ++nt)
            acc[mt][nt] = (f32x4){0.f, 0.f, 0.f, 0.f};

    for (int k0 = 0; k0 < 1024; k0 += 64) {
#pragma unroll
        for (int i = 0; i < 4; ++i) {
            gl2lds16(A + (size_t)(m0 + i * 32 + srow) * 1024 + k0 + swz,
                     &As[(i * 32 + wv * 8) * 64]);
            gl2lds16(W + (size_t)(n0 + i * 32 + srow) * 1024 + k0 + swz,
                     &Bs[(i * 32 + wv * 8) * 64]);
        }
        __syncthreads();
#pragma unroll
        for (int ks = 0; ks < 2; ++ks) {
            const int fcol = ((ks * 4 + quad) ^ (fr & 7)) * 8;
            bf16x8 af[4], bfr[4];
#pragma unroll
            for (int t = 0; t < 4; ++t) {
                af[t]  = *(const bf16x8*)&As[(wm + t * 16 + fr) * 64 + fcol];
                bfr[t] = *(const bf16x8*)&Bs[(wn + t * 16 + fr) * 64 + fcol];
            }
#pragma unroll
            for (int mt = 0; mt < 4; ++mt)
#pragma unroll
                for (int nt = 0; nt < 4; ++nt)
                    acc[mt][nt] = MFMA16(af[mt], bfr[nt], acc[mt][nt]);
        }
        __syncthreads();
    }

    float bv[4];
#pragma unroll
    for (int nt = 0; nt < 4; ++nt)
        bv[nt] = bias[n0 + wn + nt * 16 + fr];
    const int row4 = quad * 4;
#pragma unroll
    for (int mt = 0; mt < 4; ++mt)
#pragma unroll
        for (int nt = 0; nt < 4; ++nt)
#pragma unroll
            for (int r = 0; r < 4; ++r) {
                int m = m0 + wm + mt * 16 + row4 + r;
                int n = n0 + wn + nt * 16 + fr;
                float v = acc[mt][nt][r] + bv[nt];
                if (SCALE) v *= ATTN_SCALE;
                C[(size_t)m * 1024 + n] = (bf16)v;
            }
}

// ---------------------------------------------------------------------------
// V^T GEMM path: swapped-operand MFMA + LDS round-trip transpose epilogue
// ---------------------------------------------------------------------------
__device__ __forceinline__ void v_tile(const bf16* __restrict__ x,
                                       const bf16* __restrict__ Wv,
                                       const float* __restrict__ bias,
                                       bf16* __restrict__ VT,
                                       int m0, int n0, bf16* smem) {
    bf16* As = smem;
    bf16* Bs = smem + 128 * 64;

    const int lane = threadIdx.x & 63;
    const int wv   = threadIdx.x >> 6;
    const int wmW  = (wv >> 1) * 64;
    const int wnT  = (wv & 1) * 64;
    const int f    = lane & 15;
    const int quad = lane >> 4;
    const int srow = wv * 8 + (lane >> 3);
    const int swz  = (((lane & 7) ^ ((lane >> 3) & 7))) * 8;

    f32x4 acc[4][4];
#pragma unroll
    for (int mt = 0; mt < 4; ++mt)
#pragma unroll
        for (int nt = 0; nt < 4; ++nt)
            acc[mt][nt] = (f32x4){0.f, 0.f, 0.f, 0.f};

    for (int k0 = 0; k0 < 1024; k0 += 64) {
#pragma unroll
        for (int i = 0; i < 4; ++i) {
            gl2lds16(x  + (size_t)(m0 + i * 32 + srow) * 1024 + k0 + swz,
                     &As[(i * 32 + wv * 8) * 64]);
            gl2lds16(Wv + (size_t)(n0 + i * 32 + srow) * 1024 + k0 + swz,
                     &Bs[(i * 32 + wv * 8) * 64]);
        }
        __syncthreads();
#pragma unroll
        for (int ks = 0; ks < 2; ++ks) {
            const int fcol = ((ks * 4 + quad) ^ (f & 7)) * 8;
            bf16x8 wf[4], xf[4];
#pragma unroll
            for (int t = 0; t < 4; ++t) {
                wf[t] = *(const bf16x8*)&Bs[(wmW + t * 16 + f) * 64 + fcol];
                xf[t] = *(const bf16x8*)&As[(wnT + t * 16 + f) * 64 + fcol];
            }
#pragma unroll
            for (int mt = 0; mt < 4; ++mt)
#pragma unroll
                for (int nt = 0; nt < 4; ++nt)
                    acc[mt][nt] = MFMA16(wf[mt], xf[nt], acc[mt][nt]);
        }
        __syncthreads();
    }

    float4 b4[4];
#pragma unroll
    for (int mt = 0; mt < 4; ++mt)
        b4[mt] = *(const float4*)&bias[n0 + wmW + mt * 16 + quad * 4];

#pragma unroll
    for (int mt = 0; mt < 4; ++mt)
#pragma unroll
        for (int nt = 0; nt < 4; ++nt) {
            const int tok = wnT + nt * 16 + f;
#pragma unroll
            for (int r = 0; r < 4; ++r) {
                const float bvr = (r == 0) ? b4[mt].x : (r == 1) ? b4[mt].y
                                : (r == 2) ? b4[mt].z : b4[mt].w;
                smem[(wmW + mt * 16 + quad * 4 + r) * 136 + tok] =
                    (bf16)(acc[mt][nt][r] + bvr);
            }
        }
    __syncthreads();

    const int n_r  = threadIdx.x >> 4;
    const int t8   = (threadIdx.x & 15) * 8;
    const int bb   = m0 >> 11;
    const int tokg = (m0 & 2047) + t8;
#pragma unroll
    for (int p = 0; p < 8; ++p) {
        const int n_loc = p * 16 + n_r;
        bf16x8 v = *(const bf16x8*)&smem[n_loc * 136 + t8];
        *(bf16x8*)&VT[((size_t)(bb * 1024 + n0 + n_loc)) * 2048 + tokg] = v;
    }
}

// merged Q/K/V projection: 768 blocks -> 3 blocks/CU
__global__ __launch_bounds__(256) void qkv_kernel(
    const bf16* __restrict__ x,
    const bf16* __restrict__ Wq, const float* __restrict__ bq,
    const bf16* __restrict__ Wk, const float* __restrict__ bk,
    const bf16* __restrict__ Wv, const float* __restrict__ bv,
    bf16* __restrict__ Q, bf16* __restrict__ K, bf16* __restrict__ VT) {
    __shared__ __align__(16) bf16 smem[128 * 136];
    const int m0    = blockIdx.x * 128;
    const int which = blockIdx.y >> 3;
    const int n0    = (blockIdx.y & 7) * 128;
    if (which == 0)      gemm_tile<true>(x, Wq, bq, Q, m0, n0, smem);
    else if (which == 1) gemm_tile<false>(x, Wk, bk, K, m0, n0, smem);
    else                 v_tile(x, Wv, bv, VT, m0, n0, smem);
}

// ---------------------------------------------------------------------------
// O-proj GEMM, 128x64 tile, BK=64, 4 waves 2x2, fp32 out.
// ---------------------------------------------------------------------------
__global__ __launch_bounds__(256) void oproj_kernel(
    const bf16* __restrict__ A, const bf16* __restrict__ W,
    const float* __restrict__ bias, float* __restrict__ C) {
    const int m0 = blockIdx.x * 128;
    const int n0 = blockIdx.y * 64;

    __shared__ bf16 As[128 * 64];
    __shared__ bf16 Bs[64 * 64];

    const int lane = threadIdx.x & 63;
    const int wv   = threadIdx.x >> 6;
    const int wm   = (wv >> 1) * 64;
    const int wn   = (wv & 1) * 32;
    const int fr   = lane & 15;
    const int quad = lane >> 4;
    const int srow = wv * 8 + (lane >> 3);
    const int swz  = (((lane & 7) ^ ((lane >> 3) & 7))) * 8;

    f32x4 acc[4][2];
#pragma unroll
    for (int mt = 0; mt < 4; ++mt)
#pragma unroll
        for (int nt = 0; nt < 2; ++nt)
            acc[mt][nt] = (f32x4){0.f, 0.f, 0.f, 0.f};

    for (int k0 = 0; k0 < 1024; k0 += 64) {
#pragma unroll
        for (int i = 0; i < 4; ++i)
            gl2lds16(A + (size_t)(m0 + i * 32 + srow) * 1024 + k0 + swz,
                     &As[(i * 32 + wv * 8) * 64]);
#pragma unroll
        for (int i = 0; i < 2; ++i)
            gl2lds16(W + (size_t)(n0 + i * 32 + srow) * 1024 + k0 + swz,
                     &Bs[(i * 32 + wv * 8) * 64]);
        __syncthreads();
#pragma unroll
        for (int ks = 0; ks < 2; ++ks) {
            const int fcol = ((ks * 4 + quad) ^ (fr & 7)) * 8;
            bf16x8 af[4], bfr[2];
#pragma unroll
            for (int t = 0; t < 4; ++t)
                af[t] = *(const bf16x8*)&As[(wm + t * 16 + fr) * 64 + fcol];
#pragma unroll
            for (int t = 0; t < 2; ++t)
                bfr[t] = *(const bf16x8*)&Bs[(wn + t * 16 + fr) * 64 + fcol];
#pragma unroll
            for (int mt = 0; mt < 4; ++mt)
#pragma unroll
                for (int nt = 0; nt < 2; ++nt)
                    acc[mt][nt] = MFMA16(af[mt], bfr[nt], acc[mt][nt]);
        }
        __syncthreads();
    }

    float bv[2];
#pragma unroll
    for (int nt = 0; nt < 2; ++nt)
        bv[nt] = bias[n0 + wn + nt * 16 + fr];
    const int row4 = quad * 4;
#pragma unroll
    for (int mt = 0; mt < 4; ++mt)
#pragma unroll
        for (int nt = 0; nt < 2; ++nt)
#pragma unroll
            for (int r = 0; r < 4; ++r) {
                int m = m0 + wm + mt * 16 + row4 + r;
                int n = n0 + wn + nt * 16 + fr;
                C[(size_t)m * 1024 + n] = acc[mt][nt][r] + bv[nt];
            }
}

// ---------------------------------------------------------------------------
// Flash attention v8: 256 threads (4 waves), q-tile 256 (64 q/wave, G=4),
// KV range split in 2 (1024 per block, 16 steps of 64) -> 512 blocks, 2/CU.
// LDS reads amortized 4x per wave.  Writes unnormalized bf16 O-partial +
// fp32 l-partial; combine kernel finishes softmax.
// ---------------------------------------------------------------------------
__global__ __launch_bounds__(256, 2) void attn_kernel(
    const bf16* __restrict__ Q, const bf16* __restrict__ K,
    const bf16* __restrict__ VT, bf16* __restrict__ Opart,
    float* __restrict__ lpart) {
    const int tid  = threadIdx.x;
    const int lane = tid & 63;
    const int wv   = tid >> 6;       // 0..3
    const int quad = lane >> 4;
    const int f    = lane & 15;
    const int qt   = blockIdx.x >> 1;
    const int half = blockIdx.x & 1;
    const int q0   = qt * 256;
    const int kvb  = half * 1024;
    const int b    = blockIdx.y >> 4;
    const int h    = blockIdx.y & 15;

    const bf16* Qp = Q + ((size_t)b * SEQ) * 1024 + (size_t)h * 64;
    const bf16* Kp = K + ((size_t)b * SEQ) * 1024 + (size_t)h * 64;
    const bf16* Vp = VT + ((size_t)(b * 1024 + h * 64)) * 2048;   // [d][tok]
    bf16*  Op = Opart + (size_t)half * MROWS * 1024
                      + ((size_t)b * SEQ) * 1024 + (size_t)h * 64;
    float* lp = lpart + ((size_t)(half * 2 + b) * 16 + h) * SEQ;

    __shared__ bf16 Ks[2][64 * 64];    // [kv][d], swizzled 16B groups
    __shared__ bf16 VTs[2][64 * 64];   // [d][kv], swizzled 16B groups

    // Q fragments: wave handles 64 q-rows (4 groups of 16); pre-scaled.
    bf16x8 qf[4][2];
#pragma unroll
    for (int qg = 0; qg < 4; ++qg) {
        const bf16* qrow = Qp + (size_t)(q0 + wv * 64 + qg * 16 + f) * 1024;
        qf[qg][0] = *(const bf16x8*)(qrow + quad * 8);
        qf[qg][1] = *(const bf16x8*)(qrow + 32 + quad * 8);
    }

    const int srow = wv * 8 + (lane >> 3);
    const int swz  = (((lane & 7) ^ ((lane >> 3) & 7))) * 8;
    auto stageK = [&](int kv0, int buf) {
#pragma unroll
        for (int i = 0; i < 2; ++i)
            gl2lds16(Kp + (size_t)(kv0 + i * 32 + srow) * 1024 + swz,
                     &Ks[buf][(i * 32 + wv * 8) * 64]);
    };
    auto stageVT = [&](int kv0, int buf) {
#pragma unroll
        for (int i = 0; i < 2; ++i)
            gl2lds16(Vp + (size_t)(i * 32 + srow) * 2048 + kv0 + swz,
                     &VTs[buf][(i * 32 + wv * 8) * 64]);
    };

    stageK(kvb, 0);
    stageVT(kvb, 0);

    f32x4 oacc[4][4];
#pragma unroll
    for (int qg = 0; qg < 4; ++qg)
#pragma unroll
        for (int t = 0; t < 4; ++t)
            oacc[qg][t] = (f32x4){0.f, 0.f, 0.f, 0.f};
    f32x4 lacc[4];
#pragma unroll
    for (int qg = 0; qg < 4; ++qg)
        lacc[qg] = (f32x4){0.f, 0.f, 0.f, 0.f};
    const bf16x4 onesb = {(bf16)1.f, (bf16)1.f, (bf16)1.f, (bf16)1.f};
    const f32x4  zero4 = (f32x4){0.f, 0.f, 0.f, 0.f};

    const int fcol0 = (quad ^ (f & 7)) * 8;
    const int fcol1 = ((4 + quad) ^ (f & 7)) * 8;

    __syncthreads();

    auto step = [&](int cur, int nextit) {
        if (nextit < 16) {                 // async prefetch before compute
            stageK(kvb + nextit * 64, cur ^ 1);
            stageVT(kvb + nextit * 64, cur ^ 1);
        }

        // ---- S^T = K Q^T (K-frags read once, reused across 4 q-groups) ----
        bf16x8 kf0[4], kf1[4];
#pragma unroll
        for (int t = 0; t < 4; ++t) {
            kf0[t] = *(const bf16x8*)&Ks[cur][(t * 16 + f) * 64 + fcol0];
            kf1[t] = *(const bf16x8*)&Ks[cur][(t * 16 + f) * 64 + fcol1];
        }
        bf16x4 pb[4][4];
#pragma unroll
        for (int qg = 0; qg < 4; ++qg) {
            f32x4 s[4];
#pragma unroll
            for (int t = 0; t < 4; ++t) {
                s[t] = MFMA16(kf0[t], qf[qg][0], zero4);
                s[t] = MFMA16(kf1[t], qf[qg][1], s[t]);
            }
#pragma unroll
            for (int t = 0; t < 4; ++t) {
#pragma unroll
                for (int r = 0; r < 4; ++r)
                    pb[qg][t][r] = (bf16)__expf(s[t][r]);
                lacc[qg] = mfma1k(onesb, pb[qg][t], lacc[qg]);
            }
        }

        // ---- O^T += V^T P^T (V-frags read once, reused across q-groups) ----
#pragma unroll
        for (int dt = 0; dt < 4; ++dt) {
#pragma unroll
            for (int kt = 0; kt < 4; ++kt) {
                const int pc = ((kt * 2 + (quad >> 1)) ^ (f & 7)) * 8 + (quad & 1) * 4;
                bf16x4 vf = *(const bf16x4*)&VTs[cur][(dt * 16 + f) * 64 + pc];
#pragma unroll
                for (int qg = 0; qg < 4; ++qg)
                    oacc[qg][dt] = mfma1k(vf, pb[qg][kt], oacc[qg][dt]);
            }
        }
        __syncthreads();
    };

    for (int it = 0; it < 16; it += 2) {
        step(0, it + 1);
        step(1, it + 2);
    }

    // ---- store unnormalized O-partial (bf16) + l-partial (fp32) ----
#pragma unroll
    for (int qg = 0; qg < 4; ++qg) {
        const int q = q0 + wv * 64 + qg * 16 + f;
        bf16* orow = Op + (size_t)q * 1024;
#pragma unroll
        for (int dt = 0; dt < 4; ++dt) {
            bf16x4 ov;
#pragma unroll
            for (int r = 0; r < 4; ++r)
                ov[r] = (bf16)oacc[qg][dt][r];
            *(bf16x4*)(orow + dt * 16 + quad * 4) = ov;
        }
        if (quad == 0)
            lp[q] = lacc[qg][0];
    }
}

// ---------------------------------------------------------------------------
// combine: O = (Op1 + Op2) / (l1 + l2), bf16 out.
// ---------------------------------------------------------------------------
__global__ __launch_bounds__(256) void combine_kernel(
    const bf16* __restrict__ Opart, const float* __restrict__ lpart,
    bf16* __restrict__ O) {
    const int gid = blockIdx.x * 256 + threadIdx.x;     // 0..524287
    const int row = gid >> 7;                           // 0..4095
    const int c8  = (gid & 127) * 8;
    const int b   = row >> 11;
    const int tok = row & 2047;
    const int h   = c8 >> 6;

    const float l = lpart[((size_t)(0 * 2 + b) * 16 + h) * SEQ + tok]
                  + lpart[((size_t)(1 * 2 + b) * 16 + h) * SEQ + tok];
    const float inv = 1.0f / l;

    const size_t off = (size_t)row * 1024 + c8;
    bf16x8 a = *(const bf16x8*)&Opart[off];
    bf16x8 c = *(const bf16x8*)&Opart[(size_t)MROWS * 1024 + off];
    bf16x8 o;
#pragma unroll
    for (int i = 0; i < 8; ++i)
        o[i] = (bf16)(((float)a[i] + (float)c[i]) * inv);
    *(bf16x8*)&O[off] = o;
}

extern "C" void kernel_launch(void* const* d_in, const int* in_sizes, int n_in,
                              void* d_out, int out_size, void* d_ws, size_t ws_size,
                              hipStream_t stream) {
    const float* x  = (const float*)d_in[0];
    const float* Wq = (const float*)d_in[1];
    const float* bq = (const float*)d_in[2];
    const float* Wk = (const float*)d_in[3];
    const float* bk = (const float*)d_in[4];
    const float* Wv = (const float*)d_in[5];
    const float* bv = (const float*)d_in[6];
    const float* Wo = (const float*)d_in[7];
    const float* bo = (const float*)d_in[8];
    float* out = (float*)d_out;

    bf16* xb    = (bf16*)d_ws;
    bf16* Wqb   = xb   + (size_t)MROWS * 1024;
    bf16* Wkb   = Wqb  + (size_t)1024 * 1024;
    bf16* Wvb   = Wkb  + (size_t)1024 * 1024;
    bf16* Wob   = Wvb  + (size_t)1024 * 1024;
    bf16* Q     = Wob  + (size_t)1024 * 1024;
    bf16* K     = Q    + (size_t)MROWS * 1024;
    bf16* VT    = K    + (size_t)MROWS * 1024;   // [B*1024 rows][2048 tokens]
    bf16* O     = VT   + (size_t)MROWS * 1024;
    bf16* Opart = O    + (size_t)MROWS * 1024;   // 2 halves, bf16, 16 MB
    float* lpart = (float*)(Opart + (size_t)2 * MROWS * 1024);  // 512 KB

    cast_all_kernel<<<4096, 256, 0, stream>>>(x, Wq, Wk, Wv, Wo, xb);

    qkv_kernel<<<dim3(32, 24), 256, 0, stream>>>(xb, Wqb, bq, Wkb, bk, Wvb, bv, Q, K, VT);
    attn_kernel<<<dim3(16, 32), 256, 0, stream>>>(Q, K, VT, Opart, lpart);
    combine_kernel<<<2048, 256, 0, stream>>>(Opart, lpart, O);
    oproj_kernel<<<dim3(32, 16), 256, 0, stream>>>(O, Wob, bo, out);
}